// Round 3
// baseline (209.338 us; speedup 1.0000x reference)
//
#include <hip/hip_runtime.h>
#include <math.h>

#define EMB 1024
#define NH 64
#define TSEQ 4096
#define NB 4
#define NROWS (NB * TSEQ)

typedef __bf16 bf16;
typedef __bf16 bf16x8 __attribute__((ext_vector_type(8)));
typedef float f32x4 __attribute__((ext_vector_type(4)));

constexpr float kScale = 1.0f / 1048576.0f;  // 1/C^2
constexpr float kL2E = 1.44269504088896f;

__device__ __forceinline__ f32x4 mfma16(bf16x8 a, bf16x8 b, f32x4 c) {
  return __builtin_amdgcn_mfma_f32_16x16x32_bf16(a, b, c, 0, 0, 0);
}

// ---------------------------------------------------------------------------
// prep: Wt[mat][h][e] = bf16(W[mat][e][h])   (3 x 64 x 1024)
// ---------------------------------------------------------------------------
__global__ void prep_w(const float* __restrict__ Wk, const float* __restrict__ Wq,
                       const float* __restrict__ Wv, bf16* __restrict__ Wt) {
  const int blk = blockIdx.x;  // mat*64 + h
  const int mat = blk >> 6, h = blk & 63;
  const float* W = (mat == 0) ? Wk : (mat == 1 ? Wq : Wv);
  const int e0 = threadIdx.x * 4;
  bf16* dst = Wt + ((size_t)blk << 10) + e0;
#pragma unroll
  for (int u = 0; u < 4; ++u) dst[u] = (bf16)W[(e0 + u) * NH + h];
}

// ---------------------------------------------------------------------------
// proj: K/Q row-major bf16 [16384][64], V transposed bf16 Vt[b*64+h][4096].
// Block = 4 waves over ONE 16-row tile; wave w owns column-subtiles 3w..3w+2
// (3 accumulators -> low VGPR, loads stay in flight; 4096 waves = 4/SIMD).
// x A-frags duplicated across waves (L1-broadcast); Wt slice L1-shared.
// ---------------------------------------------------------------------------
__global__ __launch_bounds__(256) void proj_mfma(
    const float* __restrict__ x, const bf16* __restrict__ Wt,
    bf16* __restrict__ Kb, bf16* __restrict__ Qb, bf16* __restrict__ Vt) {
  const int tid = threadIdx.x, lane = tid & 63, wid = tid >> 6;
  const int rb = blockIdx.x * 16;
  const int lr = lane & 15, lg = lane >> 4;
  const int s0 = wid * 3;

  f32x4 acc[3];
#pragma unroll
  for (int i = 0; i < 3; ++i) acc[i] = (f32x4){0.f, 0.f, 0.f, 0.f};

  const float* xrow = x + (size_t)(rb + lr) * EMB + lg * 8;
#pragma unroll 2
  for (int ks = 0; ks < 32; ++ks) {
    const int e0 = ks * 32;
    float4 xa = *(const float4*)(xrow + e0);
    float4 xb = *(const float4*)(xrow + e0 + 4);
    bf16x8 af;
    af[0] = (bf16)xa.x; af[1] = (bf16)xa.y; af[2] = (bf16)xa.z; af[3] = (bf16)xa.w;
    af[4] = (bf16)xb.x; af[5] = (bf16)xb.y; af[6] = (bf16)xb.z; af[7] = (bf16)xb.w;
#pragma unroll
    for (int s = 0; s < 3; ++s) {
      const int sub = s0 + s;
      bf16x8 bfr = *(const bf16x8*)(Wt + (((size_t)(sub * 16 + lr)) << 10) + e0 + lg * 8);
      acc[s] = mfma16(af, bfr, acc[s]);
    }
  }
#pragma unroll
  for (int s = 0; s < 3; ++s) {
    const int sub = s0 + s;
    const int mat = sub >> 2, hs = sub & 3;
#pragma unroll
    for (int r = 0; r < 4; ++r) {
      const int row = rb + lg * 4 + r;
      const int h = hs * 16 + lr;
      bf16 v = (bf16)acc[s][r];
      if (mat == 0) {
        Kb[(size_t)row * NH + h] = v;
      } else if (mat == 1) {
        Qb[(size_t)row * NH + h] = v;
      } else {
        const int b = row >> 12, t = row & (TSEQ - 1);
        Vt[((size_t)(b * NH + h)) * TSEQ + t] = v;
      }
    }
  }
}

// ---------------------------------------------------------------------------
// attn: flash attention, bf16 MFMA. Wave = one 16-row i-tile, one j-parity.
// Block: waves {0,1} -> i-tile g (parity 0/1), waves {2,3} -> i-tile 255-g.
// V-frag loads deferred until after P->LDS write to cut peak VGPR below the
// 128 cliff; __launch_bounds__(256,4) targets 4 waves/SIMD.
// ---------------------------------------------------------------------------
__global__ __launch_bounds__(256, 4) void attn_mfma(
    const bf16* __restrict__ Kb, const bf16* __restrict__ Qb,
    const bf16* __restrict__ Vt, float* __restrict__ out) {
  __shared__ char pbuf[4 * 2048];
  __shared__ float mbuf[2][64][26];

  const int tid = threadIdx.x, lane = tid & 63, wid = tid >> 6;
  const int lr = lane & 15, lg = lane >> 4;
  const int bx = blockIdx.x;
  const int batch = bx >> 7, g = bx & 127;
  const int it = (wid < 2) ? g : (255 - g);
  const int parity = wid & 1;
  const int ibase = it << 4;
  const int nt = (it >> 2) + 1;

  const bf16* Kp = Kb + ((size_t)batch << 12) * NH;
  const bf16* Qp = Qb + ((size_t)batch << 12) * NH;
  const bf16* Vp = Vt + ((size_t)batch * NH) * TSEQ;
  char* myP = pbuf + wid * 2048;

  const bf16* krow = Kp + (size_t)(ibase + lr) * NH + lg * 8;
  bf16x8 ka0 = *(const bf16x8*)(krow);
  bf16x8 ka1 = *(const bf16x8*)(krow + 32);

  f32x4 acc[4];
  float m_[4], l_[4];
#pragma unroll
  for (int f = 0; f < 4; ++f) acc[f] = (f32x4){0.f, 0.f, 0.f, 0.f};
#pragma unroll
  for (int r = 0; r < 4; ++r) { m_[r] = -INFINITY; l_[r] = 0.f; }

  for (int jt = parity; jt < nt; jt += 2) {
    const int j0 = jt << 6;
    // ---- S = K·Q^T ----
    f32x4 s[4];
#pragma unroll
    for (int js = 0; js < 4; ++js) {
      const bf16* qrow = Qp + (size_t)(j0 + js * 16 + lr) * NH + lg * 8;
      bf16x8 q0 = *(const bf16x8*)qrow;
      bf16x8 q1 = *(const bf16x8*)(qrow + 32);
      s[js] = mfma16(ka0, q0, (f32x4){0.f, 0.f, 0.f, 0.f});
      s[js] = mfma16(ka1, q1, s[js]);
    }
    const bool maskT = (jt == nt - 1);
    float p[4][4];
#pragma unroll
    for (int js = 0; js < 4; ++js)
#pragma unroll
      for (int r = 0; r < 4; ++r) {
        float v = s[js][r] * kScale;
        if (maskT) {
          const int i = ibase + lg * 4 + r;
          const int j = j0 + js * 16 + lr;
          if (j > i) v = -INFINITY;
        }
        p[js][r] = v;
      }
    // ---- online softmax (row i in 16-lane group; reduce over lane&15) ----
#pragma unroll
    for (int r = 0; r < 4; ++r) {
      float pm = fmaxf(fmaxf(p[0][r], p[1][r]), fmaxf(p[2][r], p[3][r]));
      pm = fmaxf(pm, __shfl_xor(pm, 1));
      pm = fmaxf(pm, __shfl_xor(pm, 2));
      pm = fmaxf(pm, __shfl_xor(pm, 4));
      pm = fmaxf(pm, __shfl_xor(pm, 8));
      const float mn = fmaxf(m_[r], pm);
      const float c = __builtin_amdgcn_exp2f((m_[r] - mn) * kL2E);
      m_[r] = mn;
      float ts = 0.f;
#pragma unroll
      for (int js = 0; js < 4; ++js) {
        const float pe = __builtin_amdgcn_exp2f((p[js][r] - mn) * kL2E);
        p[js][r] = pe;
        ts += pe;
      }
      ts += __shfl_xor(ts, 1);
      ts += __shfl_xor(ts, 2);
      ts += __shfl_xor(ts, 4);
      ts += __shfl_xor(ts, 8);
      l_[r] = l_[r] * c + ts;
#pragma unroll
      for (int f = 0; f < 4; ++f) acc[f][r] *= c;
    }
    // ---- P -> LDS (bf16, XOR-swizzled: 128B-stride rows need ^((i&7)<<4)) ----
#pragma unroll
    for (int js = 0; js < 4; ++js)
#pragma unroll
      for (int r = 0; r < 4; ++r) {
        const int i = lg * 4 + r;
        const int j = js * 16 + lr;
        const int off = ((i << 7) + (j << 1)) ^ ((i & 7) << 4);
        *(bf16*)(myP + off) = (bf16)p[js][r];
      }
    // ---- PV: load V frags now (after S regs retired), A-frags from LDS ----
    const int roff0 = ((lr << 7) | (lg << 4)) ^ ((lr & 7) << 4);
    const int roff1 = ((lr << 7) | 64 | (lg << 4)) ^ ((lr & 7) << 4);
    bf16x8 pa0 = *(const bf16x8*)(myP + roff0);
    bf16x8 pa1 = *(const bf16x8*)(myP + roff1);
#pragma unroll
    for (int f = 0; f < 4; ++f) {
      const bf16* vrow = Vp + (size_t)(f * 16 + lr) * TSEQ + j0 + lg * 8;
      bf16x8 v0 = *(const bf16x8*)vrow;
      bf16x8 v1 = *(const bf16x8*)(vrow + 32);
      acc[f] = mfma16(pa0, v0, acc[f]);
      acc[f] = mfma16(pa1, v1, acc[f]);
    }
  }

  // merge parity-1 state into parity-0 wave
  if (parity == 1) {
    const int slot = wid >> 1;
    float* mb = &mbuf[slot][lane][0];
#pragma unroll
    for (int r = 0; r < 4; ++r) { mb[r] = m_[r]; mb[4 + r] = l_[r]; }
#pragma unroll
    for (int f = 0; f < 4; ++f)
#pragma unroll
      for (int r = 0; r < 4; ++r) mb[8 + f * 4 + r] = acc[f][r];
  }
  __syncthreads();
  if (parity == 0) {
    const int slot = wid >> 1;
    const float* mb = &mbuf[slot][lane][0];
#pragma unroll
    for (int r = 0; r < 4; ++r) {
      const float m2 = mb[r], l2 = mb[4 + r];
      const float mm = fmaxf(m_[r], m2);
      const float a1 = __builtin_amdgcn_exp2f((m_[r] - mm) * kL2E);
      const float a2 = (l2 > 0.f) ? __builtin_amdgcn_exp2f((m2 - mm) * kL2E) : 0.f;
      const float inv = 1.f / (l_[r] * a1 + l2 * a2);
      const int row = (batch << 12) + ibase + lg * 4 + r;
#pragma unroll
      for (int f = 0; f < 4; ++f) {
        const float o = (acc[f][r] * a1 + mb[8 + f * 4 + r] * a2) * inv;
        out[(size_t)row * NH + f * 16 + lr] = o;
      }
    }
  }
}

// ---------------------------------------------------------------------------
extern "C" void kernel_launch(void* const* d_in, const int* in_sizes, int n_in,
                              void* d_out, int out_size, void* d_ws,
                              size_t ws_size, hipStream_t stream) {
  const float* x = (const float*)d_in[0];
  const float* Wk = (const float*)d_in[1];
  const float* Wq = (const float*)d_in[2];
  const float* Wv = (const float*)d_in[3];
  float* out = (float*)d_out;

  char* ws = (char*)d_ws;
  bf16* Kb = (bf16*)ws;                          // 2 MB
  bf16* Qb = (bf16*)(ws + (2ull << 20));         // 2 MB
  bf16* Vt = (bf16*)(ws + (4ull << 20));         // 2 MB
  bf16* Wt = (bf16*)(ws + (6ull << 20));         // 384 KB

  prep_w<<<192, 256, 0, stream>>>(Wk, Wq, Wv, Wt);
  proj_mfma<<<NROWS / 16, 256, 0, stream>>>(x, Wt, Kb, Qb, Vt);
  attn_mfma<<<512, 256, 0, stream>>>(Kb, Qb, Vt, out);
}

// Round 4
// 106.140 us; speedup vs baseline: 1.9723x; 1.9723x over previous
//
#include <hip/hip_runtime.h>
#include <math.h>

#define EMB 1024
#define NH 64
#define TSEQ 4096
#define NB 4
#define NROWS (NB * TSEQ)

typedef __bf16 bf16;
typedef __bf16 bf16x8 __attribute__((ext_vector_type(8)));
typedef float f32x4 __attribute__((ext_vector_type(4)));

constexpr float kScale = 1.0f / 1048576.0f;  // 1/C^2
constexpr float kL2E = 1.44269504088896f;

__device__ __forceinline__ f32x4 mfma16(bf16x8 a, bf16x8 b, f32x4 c) {
  return __builtin_amdgcn_mfma_f32_16x16x32_bf16(a, b, c, 0, 0, 0);
}

// ---------------------------------------------------------------------------
// prep: Wt[mat][h][e] = bf16(W[mat][e][h])   (3 x 64 x 1024)
// ---------------------------------------------------------------------------
__global__ void prep_w(const float* __restrict__ Wk, const float* __restrict__ Wq,
                       const float* __restrict__ Wv, bf16* __restrict__ Wt) {
  const int blk = blockIdx.x;  // mat*64 + h
  const int mat = blk >> 6, h = blk & 63;
  const float* W = (mat == 0) ? Wk : (mat == 1 ? Wq : Wv);
  const int e0 = threadIdx.x * 4;
  bf16* dst = Wt + ((size_t)blk << 10) + e0;
#pragma unroll
  for (int u = 0; u < 4; ++u) dst[u] = (bf16)W[(e0 + u) * NH + h];
}

// ---------------------------------------------------------------------------
// proj: LDS-staged double-buffered GEMM (m97 schedule).
// Block = 512 thr (8 waves), tile M=64 x N=192, K chunks of 128 fp32.
// x staged via global_load_lds (linear LDS dest, PRE-SWIZZLED global source;
// read side applies the same XOR involution: 16B-slot ^= (row&7)).
// Wave (wm,wn): rows wm*32..+32 (2 Mtiles), cols wn*48..+48 (3 subtiles).
// ---------------------------------------------------------------------------
__global__ __launch_bounds__(512) void proj_mfma(
    const float* __restrict__ x, const bf16* __restrict__ Wt,
    bf16* __restrict__ Kb, bf16* __restrict__ Qb, bf16* __restrict__ Vt) {
  __shared__ char xls[2 * 32768];
  const int tid = threadIdx.x, lane = tid & 63, wid = tid >> 6;
  const int lr = lane & 15, lg = lane >> 4;
  const int wn = wid & 3, wm = wid >> 2;
  const int rb = blockIdx.x * 64;

  f32x4 acc[2][3];
#pragma unroll
  for (int mt = 0; mt < 2; ++mt)
#pragma unroll
    for (int s = 0; s < 3; ++s) acc[mt][s] = (f32x4){0.f, 0.f, 0.f, 0.f};

  // stage chunk c of x into buffer buf (8 waves x 4 issues x 1KB = 32KB)
  auto stage = [&](int buf, int c) {
#pragma unroll
    for (int i = 0; i < 4; ++i) {
      const int g = wid * 4 + i;              // 16B-slot group 0..31
      const int r = g * 2 + (lane >> 5);      // row 0..63
      const int cL = (lane & 31) ^ (r & 7);   // pre-swizzled source slot
      const float* gp = x + (size_t)(rb + r) * EMB + c * 128 + cL * 4;
      __builtin_amdgcn_global_load_lds(
          (const __attribute__((address_space(1))) void*)gp,
          (__attribute__((address_space(3))) void*)(xls + buf * 32768 + g * 1024),
          16, 0, 0);
    }
  };

  stage(0, 0);
  __syncthreads();

  for (int c = 0; c < 8; ++c) {
    const int cur = c & 1;
    if (c < 7) stage(cur ^ 1, c + 1);
    // B-frags for this chunk (global; Wt is L2-resident)
    bf16x8 bfr[4][3];
#pragma unroll
    for (int ks = 0; ks < 4; ++ks)
#pragma unroll
      for (int s = 0; s < 3; ++s) {
        const int sub = wn * 3 + s;
        bfr[ks][s] = *(const bf16x8*)(Wt + ((size_t)(sub * 16 + lr) << 10) +
                                      c * 128 + ks * 32 + lg * 8);
      }
    const char* base = xls + cur * 32768;
#pragma unroll
    for (int ks = 0; ks < 4; ++ks) {
#pragma unroll
      for (int mt = 0; mt < 2; ++mt) {
        const int r = wm * 32 + mt * 16 + lr;
        const int s0 = ks * 8 + lg * 2;
        float4 a0 = *(const float4*)(base + r * 512 + ((s0 ^ (r & 7)) << 4));
        float4 a1 = *(const float4*)(base + r * 512 + (((s0 + 1) ^ (r & 7)) << 4));
        bf16x8 af;
        af[0] = (bf16)a0.x; af[1] = (bf16)a0.y; af[2] = (bf16)a0.z; af[3] = (bf16)a0.w;
        af[4] = (bf16)a1.x; af[5] = (bf16)a1.y; af[6] = (bf16)a1.z; af[7] = (bf16)a1.w;
#pragma unroll
        for (int s = 0; s < 3; ++s) acc[mt][s] = mfma16(af, bfr[ks][s], acc[mt][s]);
      }
    }
    __syncthreads();
  }

#pragma unroll
  for (int mt = 0; mt < 2; ++mt)
#pragma unroll
    for (int s = 0; s < 3; ++s) {
      const int sub = wn * 3 + s;
      const int mat = sub >> 2, hs = sub & 3;
#pragma unroll
      for (int r4 = 0; r4 < 4; ++r4) {
        const int row = rb + wm * 32 + mt * 16 + lg * 4 + r4;
        const int h = hs * 16 + lr;
        bf16 v = (bf16)acc[mt][s][r4];
        if (mat == 0) {
          Kb[(size_t)row * NH + h] = v;
        } else if (mat == 1) {
          Qb[(size_t)row * NH + h] = v;
        } else {
          const int b = row >> 12, t = row & (TSEQ - 1);
          Vt[((size_t)(b * NH + h)) * TSEQ + t] = v;
        }
      }
    }
}

// ---------------------------------------------------------------------------
// attn: flash attention, bf16 MFMA (verbatim R2 version: 52us, VGPR 156).
// Wave = one 16-row i-tile, one j-parity. Block: waves {0,1} -> i-tile g,
// waves {2,3} -> i-tile 255-g. Parity merge via LDS at end.
// ---------------------------------------------------------------------------
__global__ __launch_bounds__(256) void attn_mfma(
    const bf16* __restrict__ Kb, const bf16* __restrict__ Qb,
    const bf16* __restrict__ Vt, float* __restrict__ out) {
  __shared__ char pbuf[4 * 2048];
  __shared__ float mbuf[2][64][26];

  const int tid = threadIdx.x, lane = tid & 63, wid = tid >> 6;
  const int lr = lane & 15, lg = lane >> 4;
  const int bx = blockIdx.x;
  const int batch = bx >> 7, g = bx & 127;
  const int it = (wid < 2) ? g : (255 - g);
  const int parity = wid & 1;
  const int ibase = it << 4;
  const int nt = (it >> 2) + 1;

  const bf16* Kp = Kb + ((size_t)batch << 12) * NH;
  const bf16* Qp = Qb + ((size_t)batch << 12) * NH;
  const bf16* Vp = Vt + ((size_t)batch * NH) * TSEQ;
  char* myP = pbuf + wid * 2048;

  const bf16* krow = Kp + (size_t)(ibase + lr) * NH + lg * 8;
  bf16x8 ka0 = *(const bf16x8*)(krow);
  bf16x8 ka1 = *(const bf16x8*)(krow + 32);

  f32x4 acc[4];
  float m_[4], l_[4];
#pragma unroll
  for (int f = 0; f < 4; ++f) acc[f] = (f32x4){0.f, 0.f, 0.f, 0.f};
#pragma unroll
  for (int r = 0; r < 4; ++r) { m_[r] = -INFINITY; l_[r] = 0.f; }

  for (int jt = parity; jt < nt; jt += 2) {
    const int j0 = jt << 6;
    bf16x8 qf[4][2], vf[4][2];
#pragma unroll
    for (int js = 0; js < 4; ++js) {
      const bf16* qrow = Qp + (size_t)(j0 + js * 16 + lr) * NH + lg * 8;
      qf[js][0] = *(const bf16x8*)qrow;
      qf[js][1] = *(const bf16x8*)(qrow + 32);
    }
#pragma unroll
    for (int f = 0; f < 4; ++f) {
      const bf16* vrow = Vp + (size_t)(f * 16 + lr) * TSEQ + j0 + lg * 8;
      vf[f][0] = *(const bf16x8*)vrow;
      vf[f][1] = *(const bf16x8*)(vrow + 32);
    }
    f32x4 s[4];
#pragma unroll
    for (int js = 0; js < 4; ++js) {
      s[js] = mfma16(ka0, qf[js][0], (f32x4){0.f, 0.f, 0.f, 0.f});
      s[js] = mfma16(ka1, qf[js][1], s[js]);
    }
    const bool maskT = (jt == nt - 1);
    float p[4][4];
#pragma unroll
    for (int js = 0; js < 4; ++js)
#pragma unroll
      for (int r = 0; r < 4; ++r) {
        float v = s[js][r] * kScale;
        if (maskT) {
          const int i = ibase + lg * 4 + r;
          const int j = j0 + js * 16 + lr;
          if (j > i) v = -INFINITY;
        }
        p[js][r] = v;
      }
#pragma unroll
    for (int r = 0; r < 4; ++r) {
      float pm = fmaxf(fmaxf(p[0][r], p[1][r]), fmaxf(p[2][r], p[3][r]));
      pm = fmaxf(pm, __shfl_xor(pm, 1));
      pm = fmaxf(pm, __shfl_xor(pm, 2));
      pm = fmaxf(pm, __shfl_xor(pm, 4));
      pm = fmaxf(pm, __shfl_xor(pm, 8));
      const float mn = fmaxf(m_[r], pm);
      const float c = __builtin_amdgcn_exp2f((m_[r] - mn) * kL2E);
      m_[r] = mn;
      float ts = 0.f;
#pragma unroll
      for (int js = 0; js < 4; ++js) {
        const float pe = __builtin_amdgcn_exp2f((p[js][r] - mn) * kL2E);
        p[js][r] = pe;
        ts += pe;
      }
      ts += __shfl_xor(ts, 1);
      ts += __shfl_xor(ts, 2);
      ts += __shfl_xor(ts, 4);
      ts += __shfl_xor(ts, 8);
      l_[r] = l_[r] * c + ts;
#pragma unroll
      for (int f = 0; f < 4; ++f) acc[f][r] *= c;
    }
#pragma unroll
    for (int js = 0; js < 4; ++js)
#pragma unroll
      for (int r = 0; r < 4; ++r) {
        const int i = lg * 4 + r;
        const int j = js * 16 + lr;
        const int off = ((i << 7) + (j << 1)) ^ ((i & 7) << 4);
        *(bf16*)(myP + off) = (bf16)p[js][r];
      }
    const int roff0 = ((lr << 7) | (lg << 4)) ^ ((lr & 7) << 4);
    const int roff1 = ((lr << 7) | 64 | (lg << 4)) ^ ((lr & 7) << 4);
    bf16x8 pa0 = *(const bf16x8*)(myP + roff0);
    bf16x8 pa1 = *(const bf16x8*)(myP + roff1);
#pragma unroll
    for (int f = 0; f < 4; ++f) {
      acc[f] = mfma16(pa0, vf[f][0], acc[f]);
      acc[f] = mfma16(pa1, vf[f][1], acc[f]);
    }
  }

  if (parity == 1) {
    const int slot = wid >> 1;
    float* mb = &mbuf[slot][lane][0];
#pragma unroll
    for (int r = 0; r < 4; ++r) { mb[r] = m_[r]; mb[4 + r] = l_[r]; }
#pragma unroll
    for (int f = 0; f < 4; ++f)
#pragma unroll
      for (int r = 0; r < 4; ++r) mb[8 + f * 4 + r] = acc[f][r];
  }
  __syncthreads();
  if (parity == 0) {
    const int slot = wid >> 1;
    const float* mb = &mbuf[slot][lane][0];
#pragma unroll
    for (int r = 0; r < 4; ++r) {
      const float m2 = mb[r], l2 = mb[4 + r];
      const float mm = fmaxf(m_[r], m2);
      const float a1 = __builtin_amdgcn_exp2f((m_[r] - mm) * kL2E);
      const float a2 = (l2 > 0.f) ? __builtin_amdgcn_exp2f((m2 - mm) * kL2E) : 0.f;
      const float inv = 1.f / (l_[r] * a1 + l2 * a2);
      const int row = (batch << 12) + ibase + lg * 4 + r;
#pragma unroll
      for (int f = 0; f < 4; ++f) {
        const float o = (acc[f][r] * a1 + mb[8 + f * 4 + r] * a2) * inv;
        out[(size_t)row * NH + f * 16 + lr] = o;
      }
    }
  }
}

// ---------------------------------------------------------------------------
extern "C" void kernel_launch(void* const* d_in, const int* in_sizes, int n_in,
                              void* d_out, int out_size, void* d_ws,
                              size_t ws_size, hipStream_t stream) {
  const float* x = (const float*)d_in[0];
  const float* Wk = (const float*)d_in[1];
  const float* Wq = (const float*)d_in[2];
  const float* Wv = (const float*)d_in[3];
  float* out = (float*)d_out;

  char* ws = (char*)d_ws;
  bf16* Kb = (bf16*)ws;                          // 2 MB
  bf16* Qb = (bf16*)(ws + (2ull << 20));         // 2 MB
  bf16* Vt = (bf16*)(ws + (4ull << 20));         // 2 MB
  bf16* Wt = (bf16*)(ws + (6ull << 20));         // 384 KB

  prep_w<<<192, 256, 0, stream>>>(Wk, Wq, Wv, Wt);
  proj_mfma<<<NROWS / 64, 512, 0, stream>>>(x, Wt, Kb, Qb, Vt);
  attn_mfma<<<512, 256, 0, stream>>>(Kb, Qb, Vt, out);
}